// Round 4
// baseline (332.835 us; speedup 1.0000x reference)
//
#include <hip/hip_runtime.h>
#include <cstdint>

#define K_DIM 3072
#define B_DIM 8192
#define BM2   256
#define NT2   32      /* 8192/256 tiles per dim */
#define ROW_B 3072    /* bytes per fp8 row */
#define ROW_U 768     /* u32 per fp8 row */

typedef __attribute__((ext_vector_type(4))) float        f32x4;
typedef __attribute__((ext_vector_type(4))) unsigned int u32x4;
typedef long long i64;

__device__ __forceinline__ i64 pack64(unsigned lo, unsigned hi) {
    return (i64)(((unsigned long long)hi << 32) | (unsigned long long)lo);
}

// ---------- kernel 1: pack x into fp8 e4m3 (k-octets permuted) + row |x|^2 ----------
// Within each 64-k block: chunk c (16 B) = [k-octet c of k0..31 | k-octet c of k32..63],
// so one ds_read_b128 yields both K=32 MFMA fragments.  Same permutation for both
// Gram operands => dot products invariant.
__global__ __launch_bounds__(384) void prep_kernel(const float* __restrict__ x,
                                                   unsigned int* __restrict__ xb,
                                                   float* __restrict__ xn,
                                                   float* __restrict__ se)
{
    const int row = blockIdx.x;
    const int tid = threadIdx.x;            // 384 threads: one k-octet (8 floats) each
    const float4* xr = (const float4*)(x + (size_t)row * K_DIM);
    float4 v0 = xr[2 * tid];
    float4 v1 = xr[2 * tid + 1];
    float s = v0.x * v0.x + v0.y * v0.y + v0.z * v0.z + v0.w * v0.w
            + v1.x * v1.x + v1.y * v1.y + v1.z * v1.z + v1.w * v1.w;

    int p0 = __builtin_amdgcn_cvt_pk_fp8_f32(v0.x, v0.y, 0, false);
    p0     = __builtin_amdgcn_cvt_pk_fp8_f32(v0.z, v0.w, p0, true);
    int p1 = __builtin_amdgcn_cvt_pk_fp8_f32(v1.x, v1.y, 0, false);
    p1     = __builtin_amdgcn_cvt_pk_fp8_f32(v1.z, v1.w, p1, true);

    const int blk = tid >> 3;               // 64-k block index (0..47)
    const int oct = tid & 7;                // octet within block
    const int offB = blk * 64 + ((oct < 4) ? oct * 16 : (oct - 4) * 16 + 8);
    unsigned int* dst = xb + (size_t)row * ROW_U + (offB >> 2);
    dst[0] = (unsigned)p0;
    dst[1] = (unsigned)p1;

#pragma unroll
    for (int d = 32; d > 0; d >>= 1) s += __shfl_down(s, d);
    __shared__ float red[6];
    if ((tid & 63) == 0) red[tid >> 6] = s;
    __syncthreads();
    if (tid == 0) {
        float t = 0.f;
#pragma unroll
        for (int i = 0; i < 6; ++i) t += red[i];
        xn[row] = t;
        se[row] = 0.f;
    }
}

// ---------- kernel 2: 256x256 triangular fp8 Gram, 8-phase counted-vmcnt schedule ----------
__global__ __launch_bounds__(512, 2) void gram_lse_kernel(const unsigned int* __restrict__ xb,
                                                          const float* __restrict__ xn,
                                                          const float* __restrict__ logvar,
                                                          float* __restrict__ se)
{
    // [dbuf][A/B][256 rows x 128 B]  = 128 KiB
    __shared__ __align__(1024) unsigned char lds[2][2][32768];

    // decode linear block id -> triangular tile (bm <= bn)
    int rem = blockIdx.x;
    int bm = 0;
    while (rem >= NT2 - bm) { rem -= NT2 - bm; ++bm; }
    const int bn = bm + rem;

    const int tid  = threadIdx.x;           // 512
    const int lane = tid & 63;
    const int wave = tid >> 6;              // 8 waves: 2(M) x 4(N)
    const int wr = wave >> 2, wc = wave & 3;
    const int fc = lane >> 4;               // k-octet group 0..3

    const size_t rowA0 = (size_t)bm * BM2;
    const size_t rowB0 = (size_t)bn * BM2;
    const unsigned char* xb8 = (const unsigned char*)xb;

    // staging precompute: 8 slots/thread/K-tile (4 A + 4 B), 16 B each.
    // slot l covers tile element e=(l&3)*512+tid -> row r=e>>3, chunk c=e&7.
    // Source chunk is PRE-SWIZZLED (c ^ (r&7)); LDS dest stays linear (rule #21).
    unsigned int srcOff[8];
    int dstOff[8];
#pragma unroll
    for (int l = 0; l < 8; ++l) {
        const int e = (l & 3) * 512 + tid;
        const int r = e >> 3, c = e & 7;
        const int csw = c ^ (r & 7);
        const size_t rb = (l < 4 ? rowA0 : rowB0) + (size_t)r;
        srcOff[l] = (unsigned int)(rb * ROW_B + (size_t)csw * 16);
        dstOff[l] = e * 16;
    }

    f32x4 acc[8][4];
#pragma unroll
    for (int i = 0; i < 8; ++i)
#pragma unroll
        for (int j = 0; j < 4; ++j) acc[i][j] = (f32x4){0.f, 0.f, 0.f, 0.f};

    // prologue: stage K-tile 0 into buffer 0
#pragma unroll
    for (int l = 0; l < 8; ++l) {
        const unsigned char* src = xb8 + srcOff[l];
        unsigned char* dst = &lds[0][l < 4 ? 0 : 1][0] + dstOff[l];
        __builtin_amdgcn_global_load_lds(
            (const __attribute__((address_space(1))) void*)src,
            (__attribute__((address_space(3))) void*)dst, 16, 0, 0);
    }
    asm volatile("s_waitcnt vmcnt(0)" ::: "memory");
    asm volatile("s_barrier" ::: "memory");

    for (int t = 0; t < 24; ++t) {          // 24 K-tiles of 128 fp8-k
        const unsigned char* curA = &lds[t & 1][0][0];
        const unsigned char* curB = &lds[t & 1][1][0];
        unsigned char* nxtA = &lds[(t + 1) & 1][0][0];
        unsigned char* nxtB = &lds[(t + 1) & 1][1][0];
        const unsigned int ktoff = (unsigned int)(t + 1) * 128u;

#pragma unroll
        for (int p = 0; p < 8; ++p) {
            const int mh = p >> 2;          // m-half (4 of 8 m-reps)
            const int np = (p >> 1) & 1;    // n-pair (2 of 4 n-reps)
            const int kp = p & 1;           // 64-k block within tile

            // ds-read this phase's fragments (reads overlap barrier wait)
            i64 aLo[4], aHi[4], bLo[2], bHi[2];
#pragma unroll
            for (int mi = 0; mi < 4; ++mi) {
                const int r = wr * 128 + (mh * 4 + mi) * 16 + (lane & 15);
                const int c = (kp * 4 + fc) ^ (r & 7);
                u32x4 v = *(const u32x4*)(curA + r * 128 + c * 16);
                aLo[mi] = pack64(v[0], v[1]);
                aHi[mi] = pack64(v[2], v[3]);
            }
#pragma unroll
            for (int ni = 0; ni < 2; ++ni) {
                const int r = wc * 64 + (np * 2 + ni) * 16 + (lane & 15);
                const int c = (kp * 4 + fc) ^ (r & 7);
                u32x4 v = *(const u32x4*)(curB + r * 128 + c * 16);
                bLo[ni] = pack64(v[0], v[1]);
                bHi[ni] = pack64(v[2], v[3]);
            }

            // prefetch next K-tile: 2 loads/phase over phases 0-3 (>=4 phases slack)
            if (p < 4 && t < 23) {
#pragma unroll
                for (int q = 0; q < 2; ++q) {
                    const int l = p * 2 + q;
                    const unsigned char* src = xb8 + srcOff[l] + ktoff;
                    unsigned char* dst = ((l < 4) ? nxtA : nxtB) + dstOff[l];
                    __builtin_amdgcn_global_load_lds(
                        (const __attribute__((address_space(1))) void*)src,
                        (__attribute__((address_space(3))) void*)dst, 16, 0, 0);
                }
            }

            asm volatile("s_barrier" ::: "memory");

            __builtin_amdgcn_s_setprio(1);
#pragma unroll
            for (int mi = 0; mi < 4; ++mi)
#pragma unroll
                for (int ni = 0; ni < 2; ++ni) {
                    acc[mh * 4 + mi][np * 2 + ni] =
                        __builtin_amdgcn_mfma_f32_16x16x32_fp8_fp8(
                            aLo[mi], bLo[ni], acc[mh * 4 + mi][np * 2 + ni], 0, 0, 0);
                    acc[mh * 4 + mi][np * 2 + ni] =
                        __builtin_amdgcn_mfma_f32_16x16x32_fp8_fp8(
                            aHi[mi], bHi[ni], acc[mh * 4 + mi][np * 2 + ni], 0, 0, 0);
                }
            __builtin_amdgcn_s_setprio(0);

            if (p == 7)   // once per K-tile: next tile's 8 loads done (never drain mid-tile)
                asm volatile("s_waitcnt vmcnt(0)" ::: "memory");
            asm volatile("s_barrier" ::: "memory");
        }
    }

    // ---- fused epilogue: exp terms + row/col partial sums ----
    const float lv  = logvar[0];
    const float var = __expf(lv) + 1e-10f;
    const float cc  = 0.5f / var;

    const int colBase = (int)rowB0 + wc * 64 + (lane & 15);
    const int rowBase = (int)rowA0 + wr * 128 + (lane >> 4) * 4;

    // row sums -> se[i]
#pragma unroll
    for (int mi = 0; mi < 8; ++mi) {
#pragma unroll
        for (int rg = 0; rg < 4; ++rg) {
            const int i = rowBase + mi * 16 + rg;
            const float xni = xn[i];
            float rs = 0.f;
#pragma unroll
            for (int ni = 0; ni < 4; ++ni) {
                const int j = colBase + ni * 16;
                const float g = acc[mi][ni][rg];
                const float dist = xni + xn[j] - 2.f * g;
                rs += (i == j) ? 1.0f : __expf(-cc * fmaxf(dist, 0.f));
            }
#pragma unroll
            for (int d = 1; d < 16; d <<= 1) rs += __shfl_xor(rs, d);
            if ((lane & 15) == 0) atomicAdd(&se[i], rs);
        }
    }

    // col sums -> se[j] for off-diagonal tiles (mirror elements, i != j always)
    if (bm != bn) {
#pragma unroll
        for (int ni = 0; ni < 4; ++ni) {
            const int j = colBase + ni * 16;
            const float xnj = xn[j];
            float cs = 0.f;
#pragma unroll
            for (int mi = 0; mi < 8; ++mi)
#pragma unroll
                for (int rg = 0; rg < 4; ++rg) {
                    const int i = rowBase + mi * 16 + rg;
                    const float g = acc[mi][ni][rg];
                    cs += __expf(-cc * fmaxf(xn[i] + xnj - 2.f * g, 0.f));
                }
#pragma unroll
            for (int d = 16; d < 64; d <<= 1) cs += __shfl_xor(cs, d);
            if ((lane >> 4) == 0) atomicAdd(&se[j], cs);
        }
    }
}

// ---------- kernel 3: KL scalar ----------
__global__ __launch_bounds__(256) void kl_kernel(const float* __restrict__ se,
                                                 float* __restrict__ out)
{
    const int tid = threadIdx.x;
    float s = 0.f;
    for (int i = tid; i < B_DIM; i += 256) s += logf(se[i]);
#pragma unroll
    for (int d = 32; d > 0; d >>= 1) s += __shfl_down(s, d);
    __shared__ float red[4];
    if ((tid & 63) == 0) red[tid >> 6] = s;
    __syncthreads();
    if (tid == 0) {
        const float dc = -(red[0] + red[1] + red[2] + red[3]) / (float)B_DIM;
        out[0] = (logf((float)B_DIM) + dc) / logf(2.f);
    }
}

// ---------- kernel 4: x_t = x + exp(0.5*logvar) * noise ----------
__global__ __launch_bounds__(256) void xt_kernel(const float4* __restrict__ x,
                                                 const float4* __restrict__ nz,
                                                 const float* __restrict__ logvar,
                                                 float4* __restrict__ out, int n4)
{
    const float sc = expf(0.5f * logvar[0]);
    for (int i = blockIdx.x * blockDim.x + threadIdx.x; i < n4;
         i += gridDim.x * blockDim.x) {
        float4 a = x[i], b = nz[i];
        float4 o;
        o.x = fmaf(sc, b.x, a.x);
        o.y = fmaf(sc, b.y, a.y);
        o.z = fmaf(sc, b.z, a.z);
        o.w = fmaf(sc, b.w, a.w);
        out[i] = o;
    }
}

extern "C" void kernel_launch(void* const* d_in, const int* in_sizes, int n_in,
                              void* d_out, int out_size, void* d_ws, size_t ws_size,
                              hipStream_t stream)
{
    const float* x      = (const float*)d_in[0];
    const float* noise  = (const float*)d_in[1];
    const float* logvar = (const float*)d_in[2];
    float* out = (float*)d_out;

    const size_t NEL = (size_t)B_DIM * K_DIM;   // 25165824

    // scratch carved out of d_out (fully overwritten by xt_kernel at the end):
    //   bytes [0, 25.2MB)  : fp8-packed x (8192 rows x 3072 B, k-octets permuted)
    //   bytes [32MB, ...)  : x_norm (f32, 8192) then sumexp (f32, 8192)
    unsigned int* xb = (unsigned int*)d_out;
    float* xn = (float*)((char*)d_out + (32u << 20));
    float* se = xn + B_DIM;

    prep_kernel<<<B_DIM, 384, 0, stream>>>(x, xb, xn, se);

    const int ntri = NT2 * (NT2 + 1) / 2;   // 528 triangular 256x256 tiles
    gram_lse_kernel<<<ntri, 512, 0, stream>>>(xb, xn, logvar, se);

    kl_kernel<<<1, 256, 0, stream>>>(se, out + NEL);

    xt_kernel<<<2048, 256, 0, stream>>>((const float4*)x, (const float4*)noise,
                                        logvar, (float4*)out, (int)(NEL / 4));
}

// Round 5
// 231.416 us; speedup vs baseline: 1.4383x; 1.4383x over previous
//
#include <hip/hip_runtime.h>
#include <cstdint>

#define K_DIM 3072
#define B_DIM 8192
#define ROW_B 3072    /* bytes per fp8 row */
#define ROW_U 768     /* u32 per fp8 row */
#define BMA   256     /* A-rows per tile */
#define BNB   128     /* B-cols per tile */
#define NTB   64      /* 8192/128 col tiles */
#define NKT   48      /* K_DIM/64 K-tiles */

typedef __attribute__((ext_vector_type(4))) float        f32x4;
typedef __attribute__((ext_vector_type(4))) unsigned int u32x4;
typedef long long i64;

__device__ __forceinline__ i64 pack64(unsigned lo, unsigned hi) {
    return (i64)(((unsigned long long)hi << 32) | (unsigned long long)lo);
}

// ---------- kernel 1: fused x_t write + fp8 e4m3 pack (k-octets permuted) + row |x|^2 ----------
// Within each 64-k block: chunk c (16 B) = [octet c of k0..31 | octet c of k32..63];
// same permutation for both Gram operands => dot products invariant.
__global__ __launch_bounds__(384) void prep_kernel(const float* __restrict__ x,
                                                   const float* __restrict__ nz,
                                                   const float* __restrict__ logvar,
                                                   float* __restrict__ xt,     // may be null
                                                   unsigned int* __restrict__ xb,
                                                   float* __restrict__ xn,
                                                   float* __restrict__ se)
{
    const int row = blockIdx.x;
    const int tid = threadIdx.x;            // 384 threads: one k-octet (8 floats) each
    const float4* xr = (const float4*)(x + (size_t)row * K_DIM);
    float4 v0 = xr[2 * tid];
    float4 v1 = xr[2 * tid + 1];
    float s = v0.x * v0.x + v0.y * v0.y + v0.z * v0.z + v0.w * v0.w
            + v1.x * v1.x + v1.y * v1.y + v1.z * v1.z + v1.w * v1.w;

    if (xt) {   // fused x_t = x + exp(0.5*logvar)*noise
        const float4* nr = (const float4*)(nz + (size_t)row * K_DIM);
        float4 n0 = nr[2 * tid], n1 = nr[2 * tid + 1];
        const float sc = __expf(0.5f * logvar[0]);
        float4 o0, o1;
        o0.x = fmaf(sc, n0.x, v0.x); o0.y = fmaf(sc, n0.y, v0.y);
        o0.z = fmaf(sc, n0.z, v0.z); o0.w = fmaf(sc, n0.w, v0.w);
        o1.x = fmaf(sc, n1.x, v1.x); o1.y = fmaf(sc, n1.y, v1.y);
        o1.z = fmaf(sc, n1.z, v1.z); o1.w = fmaf(sc, n1.w, v1.w);
        float4* tr = (float4*)(xt + (size_t)row * K_DIM);
        tr[2 * tid] = o0;
        tr[2 * tid + 1] = o1;
    }

    int p0 = __builtin_amdgcn_cvt_pk_fp8_f32(v0.x, v0.y, 0, false);
    p0     = __builtin_amdgcn_cvt_pk_fp8_f32(v0.z, v0.w, p0, true);
    int p1 = __builtin_amdgcn_cvt_pk_fp8_f32(v1.x, v1.y, 0, false);
    p1     = __builtin_amdgcn_cvt_pk_fp8_f32(v1.z, v1.w, p1, true);

    const int blk = tid >> 3;               // 64-k block index (0..47)
    const int oct = tid & 7;                // octet within block
    const int offB = blk * 64 + ((oct < 4) ? oct * 16 : (oct - 4) * 16 + 8);
    unsigned int* dst = xb + (size_t)row * ROW_U + (offB >> 2);
    dst[0] = (unsigned)p0;
    dst[1] = (unsigned)p1;

#pragma unroll
    for (int d = 32; d > 0; d >>= 1) s += __shfl_down(s, d);
    __shared__ float red[6];
    if ((tid & 63) == 0) red[tid >> 6] = s;
    __syncthreads();
    if (tid == 0) {
        float t = 0.f;
#pragma unroll
        for (int i = 0; i < 6; ++i) t += red[i];
        xn[row] = t;
        se[row] = 0.f;
    }
}

// ---------- kernel 2: 256x128 triangular fp8 Gram, dbuf BK=64, 2 blocks/CU ----------
__global__ __launch_bounds__(512, 4) void gram_lse_kernel(const unsigned int* __restrict__ xb,
                                                          const float* __restrict__ xn,
                                                          const float* __restrict__ logvar,
                                                          float* __restrict__ se)
{
    // per buffer: A 256x64B (16 KB) at [0], B 128x64B (8 KB) at [16384]  => 48 KiB total
    __shared__ __align__(1024) unsigned char lds[2][24576];

    // decode linear block id -> (a, v): a in [0,32), v in [2a, 64)
    int rem = blockIdx.x;
    int a = 0;
    while (rem >= NTB - 2 * a) { rem -= NTB - 2 * a; ++a; }
    const int v = 2 * a + rem;

    const int tid  = threadIdx.x;           // 512
    const int lane = tid & 63;
    const int wave = tid >> 6;              // 8 waves: 4(M) x 2(N)
    const int wr = wave >> 1, wc = wave & 1;
    const int fc = lane >> 4;               // 16B chunk group 0..3

    const size_t rowA0 = (size_t)a * BMA;
    const size_t rowB0 = (size_t)v * BNB;
    const unsigned char* xb8 = (const unsigned char*)xb;

    // staging: 3 slots/thread/K-tile (2 A + 1 B), 16 B each.
    // slot element e -> row r=e>>2, chunk c=e&3; source chunk PRE-SWIZZLED
    // (c ^ (r>>1)&3); LDS dest linear (rule #21).
    unsigned int srcOff[3];
    int dstOff[3];
#pragma unroll
    for (int l = 0; l < 3; ++l) {
        const int e = (l < 2) ? (l * 512 + tid) : tid;
        const int r = e >> 2, c = e & 3;
        const int csw = c ^ ((r >> 1) & 3);
        const size_t rb = ((l < 2) ? rowA0 : rowB0) + (size_t)r;
        srcOff[l] = (unsigned int)(rb * ROW_B + (size_t)csw * 16);
        dstOff[l] = ((l < 2) ? 0 : 16384) + e * 16;
    }

    f32x4 acc[4][4];
#pragma unroll
    for (int i = 0; i < 4; ++i)
#pragma unroll
        for (int j = 0; j < 4; ++j) acc[i][j] = (f32x4){0.f, 0.f, 0.f, 0.f};

    // prologue: stage K-tile 0 into buffer 0
#pragma unroll
    for (int l = 0; l < 3; ++l) {
        __builtin_amdgcn_global_load_lds(
            (const __attribute__((address_space(1))) void*)(xb8 + srcOff[l]),
            (__attribute__((address_space(3))) void*)(&lds[0][0] + dstOff[l]), 16, 0, 0);
    }
    __syncthreads();   // vmcnt(0) drain + barrier

    for (int t = 0; t < NKT; ++t) {
        const unsigned char* cur = &lds[t & 1][0];
        unsigned char* nxt = &lds[(t + 1) & 1][0];

        // prefetch next K-tile (dst buffer's last reads were fenced by the
        // barrier at the end of iteration t-1); ~1 full tile of compute slack
        if (t < NKT - 1) {
            const unsigned int kg = (unsigned int)(t + 1) * 64u;
#pragma unroll
            for (int l = 0; l < 3; ++l) {
                __builtin_amdgcn_global_load_lds(
                    (const __attribute__((address_space(1))) void*)(xb8 + srcOff[l] + kg),
                    (__attribute__((address_space(3))) void*)(nxt + dstOff[l]), 16, 0, 0);
            }
        }

        // fragment reads (swizzled), conflict-free per R3 measurement
        i64 aLo[4], aHi[4], bLo[4], bHi[4];
#pragma unroll
        for (int mi = 0; mi < 4; ++mi) {
            const int r = wr * 64 + mi * 16 + (lane & 15);
            const int phys = fc ^ ((r >> 1) & 3);
            u32x4 w = *(const u32x4*)(cur + r * 64 + phys * 16);
            aLo[mi] = pack64(w[0], w[1]);
            aHi[mi] = pack64(w[2], w[3]);
        }
#pragma unroll
        for (int ni = 0; ni < 4; ++ni) {
            const int r = wc * 64 + ni * 16 + (lane & 15);
            const int phys = fc ^ ((r >> 1) & 3);
            u32x4 w = *(const u32x4*)(cur + 16384 + r * 64 + phys * 16);
            bLo[ni] = pack64(w[0], w[1]);
            bHi[ni] = pack64(w[2], w[3]);
        }

        __builtin_amdgcn_s_setprio(1);
#pragma unroll
        for (int mi = 0; mi < 4; ++mi)
#pragma unroll
            for (int ni = 0; ni < 4; ++ni) {
                acc[mi][ni] = __builtin_amdgcn_mfma_f32_16x16x32_fp8_fp8(
                    aLo[mi], bLo[ni], acc[mi][ni], 0, 0, 0);
                acc[mi][ni] = __builtin_amdgcn_mfma_f32_16x16x32_fp8_fp8(
                    aHi[mi], bHi[ni], acc[mi][ni], 0, 0, 0);
            }
        __builtin_amdgcn_s_setprio(0);

        __syncthreads();   // drains vmcnt (prefetch landed) + fences cur reads
    }

    // ---- fused epilogue: exp terms + row/col partial sums ----
    const float lv  = logvar[0];
    const float var = __expf(lv) + 1e-10f;
    const float cc  = 0.5f / var;

    const int u = 2 * a + (wr >> 1);        // this wave's 128-row cell index
    if (u > v) return;                      // below-diagonal half of a v==2a tile

    const int colBase = (int)rowB0 + wc * 64 + (lane & 15);
    const int rowBase = (int)rowA0 + wr * 64 + (lane >> 4) * 4;

    // row sums -> se[i]  (i==j override handles diagonal cells exactly)
#pragma unroll
    for (int mi = 0; mi < 4; ++mi) {
#pragma unroll
        for (int rg = 0; rg < 4; ++rg) {
            const int i = rowBase + mi * 16 + rg;
            const float xni = xn[i];
            float rs = 0.f;
#pragma unroll
            for (int ni = 0; ni < 4; ++ni) {
                const int j = colBase + ni * 16;
                const float g = acc[mi][ni][rg];
                const float dist = xni + xn[j] - 2.f * g;
                rs += (i == j) ? 1.0f : __expf(-cc * fmaxf(dist, 0.f));
            }
#pragma unroll
            for (int d = 1; d < 16; d <<= 1) rs += __shfl_xor(rs, d);
            if ((lane & 15) == 0) atomicAdd(&se[i], rs);
        }
    }

    // col-mirror sums -> se[j], strictly-off-diagonal cells only (i < j always)
    if (u < v) {
#pragma unroll
        for (int ni = 0; ni < 4; ++ni) {
            const int j = colBase + ni * 16;
            const float xnj = xn[j];
            float cs = 0.f;
#pragma unroll
            for (int mi = 0; mi < 4; ++mi)
#pragma unroll
                for (int rg = 0; rg < 4; ++rg) {
                    const int i = rowBase + mi * 16 + rg;
                    const float g = acc[mi][ni][rg];
                    cs += __expf(-cc * fmaxf(xn[i] + xnj - 2.f * g, 0.f));
                }
#pragma unroll
            for (int d = 16; d < 64; d <<= 1) cs += __shfl_xor(cs, d);
            if ((lane >> 4) == 0) atomicAdd(&se[j], cs);
        }
    }
}

// ---------- kernel 3: KL scalar ----------
__global__ __launch_bounds__(256) void kl_kernel(const float* __restrict__ se,
                                                 float* __restrict__ out)
{
    const int tid = threadIdx.x;
    float s = 0.f;
    for (int i = tid; i < B_DIM; i += 256) s += logf(se[i]);
#pragma unroll
    for (int d = 32; d > 0; d >>= 1) s += __shfl_down(s, d);
    __shared__ float red[4];
    if ((tid & 63) == 0) red[tid >> 6] = s;
    __syncthreads();
    if (tid == 0) {
        const float dc = -(red[0] + red[1] + red[2] + red[3]) / (float)B_DIM;
        out[0] = (logf((float)B_DIM) + dc) / logf(2.f);
    }
}

// ---------- kernel 4 (fallback path only): x_t elementwise ----------
__global__ __launch_bounds__(256) void xt_kernel(const float4* __restrict__ x,
                                                 const float4* __restrict__ nz,
                                                 const float* __restrict__ logvar,
                                                 float4* __restrict__ out, int n4)
{
    const float sc = expf(0.5f * logvar[0]);
    for (int i = blockIdx.x * blockDim.x + threadIdx.x; i < n4;
         i += gridDim.x * blockDim.x) {
        float4 va = x[i], vb = nz[i];
        float4 o;
        o.x = fmaf(sc, vb.x, va.x);
        o.y = fmaf(sc, vb.y, va.y);
        o.z = fmaf(sc, vb.z, va.z);
        o.w = fmaf(sc, vb.w, va.w);
        out[i] = o;
    }
}

extern "C" void kernel_launch(void* const* d_in, const int* in_sizes, int n_in,
                              void* d_out, int out_size, void* d_ws, size_t ws_size,
                              hipStream_t stream)
{
    const float* x      = (const float*)d_in[0];
    const float* noise  = (const float*)d_in[1];
    const float* logvar = (const float*)d_in[2];
    float* out = (float*)d_out;

    const size_t NEL      = (size_t)B_DIM * K_DIM;      // 25165824
    const size_t XB_BYTES = (size_t)B_DIM * ROW_B;      // 25165824 B
    const size_t NTILES   = 1056;                       // sum_{a<32} (64-2a)

    const bool use_ws = ws_size >= XB_BYTES + 2 * (size_t)B_DIM * sizeof(float) + 256;

    if (use_ws) {
        // xb/xn/se live in d_ws; x_t written directly by fused prep
        unsigned int* xb = (unsigned int*)d_ws;
        float* xn = (float*)((char*)d_ws + XB_BYTES);
        float* se = xn + B_DIM;

        prep_kernel<<<B_DIM, 384, 0, stream>>>(x, noise, logvar, out, xb, xn, se);
        gram_lse_kernel<<<(int)NTILES, 512, 0, stream>>>(xb, xn, logvar, se);
        kl_kernel<<<1, 256, 0, stream>>>(se, out + NEL);
    } else {
        // fallback: scratch carved from d_out, x_t written last
        unsigned int* xb = (unsigned int*)d_out;
        float* xn = (float*)((char*)d_out + (32u << 20));
        float* se = xn + B_DIM;

        prep_kernel<<<B_DIM, 384, 0, stream>>>(x, noise, logvar, nullptr, xb, xn, se);
        gram_lse_kernel<<<(int)NTILES, 512, 0, stream>>>(xb, xn, logvar, se);
        kl_kernel<<<1, 256, 0, stream>>>(se, out + NEL);
        xt_kernel<<<2048, 256, 0, stream>>>((const float4*)x, (const float4*)noise,
                                            logvar, (float4*)out, (int)(NEL / 4));
    }
}

// Round 6
// 209.851 us; speedup vs baseline: 1.5861x; 1.1028x over previous
//
#include <hip/hip_runtime.h>
#include <cstdint>

#define K_DIM 3072
#define B_DIM 8192
#define ROW_B 3072    /* bytes per i8 row */
#define ROW_U 768     /* u32 per i8 row */
#define BMA   256     /* A-rows per tile */
#define BNB   128     /* B-cols per tile */
#define NTB   64      /* 8192/128 col tiles */
#define NKT   48      /* K_DIM/64 K-tiles */

typedef __attribute__((ext_vector_type(4))) float        f32x4;
typedef __attribute__((ext_vector_type(4))) int          i32x4;

#define QS     16.0f          /* quant scale: q = rn(x*16), exact mul */
#define INV_S2 0.00390625f    /* 1/256 */

__device__ __forceinline__ int q8(float f) {
    int q = __float2int_rn(f * QS);
    return max(-127, min(127, q));
}
__device__ __forceinline__ unsigned pack4(float a, float b, float c, float d) {
    return (unsigned)(q8(a) & 0xFF)
         | ((unsigned)(q8(b) & 0xFF) << 8)
         | ((unsigned)(q8(c) & 0xFF) << 16)
         | ((unsigned)(q8(d) & 0xFF) << 24);
}

// ---------- kernel 1: fused x_t write + i8 quantize (row-major) + row |x|^2 ----------
__global__ __launch_bounds__(384) void prep_kernel(const float* __restrict__ x,
                                                   const float* __restrict__ nz,
                                                   const float* __restrict__ logvar,
                                                   float* __restrict__ xt,     // may be null
                                                   unsigned int* __restrict__ xb,
                                                   float* __restrict__ xn,
                                                   float* __restrict__ se)
{
    const int row = blockIdx.x;
    const int tid = threadIdx.x;            // 384 threads: 8 consecutive floats each
    const float4* xr = (const float4*)(x + (size_t)row * K_DIM);
    float4 v0 = xr[2 * tid];
    float4 v1 = xr[2 * tid + 1];
    float s = v0.x * v0.x + v0.y * v0.y + v0.z * v0.z + v0.w * v0.w
            + v1.x * v1.x + v1.y * v1.y + v1.z * v1.z + v1.w * v1.w;

    if (xt) {   // fused x_t = x + exp(0.5*logvar)*noise
        const float4* nr = (const float4*)(nz + (size_t)row * K_DIM);
        float4 n0 = nr[2 * tid], n1 = nr[2 * tid + 1];
        const float sc = __expf(0.5f * logvar[0]);
        float4 o0, o1;
        o0.x = fmaf(sc, n0.x, v0.x); o0.y = fmaf(sc, n0.y, v0.y);
        o0.z = fmaf(sc, n0.z, v0.z); o0.w = fmaf(sc, n0.w, v0.w);
        o1.x = fmaf(sc, n1.x, v1.x); o1.y = fmaf(sc, n1.y, v1.y);
        o1.z = fmaf(sc, n1.z, v1.z); o1.w = fmaf(sc, n1.w, v1.w);
        float4* tr = (float4*)(xt + (size_t)row * K_DIM);
        tr[2 * tid] = o0;
        tr[2 * tid + 1] = o1;
    }

    unsigned int* dst = xb + (size_t)row * ROW_U + tid * 2;
    dst[0] = pack4(v0.x, v0.y, v0.z, v0.w);
    dst[1] = pack4(v1.x, v1.y, v1.z, v1.w);

#pragma unroll
    for (int d = 32; d > 0; d >>= 1) s += __shfl_down(s, d);
    __shared__ float red[6];
    if ((tid & 63) == 0) red[tid >> 6] = s;
    __syncthreads();
    if (tid == 0) {
        float t = 0.f;
#pragma unroll
        for (int i = 0; i < 6; ++i) t += red[i];
        xn[row] = t;
        se[row] = 0.f;
    }
}

// ---------- kernel 2: 256x128 triangular i8 Gram, 3-buf counted-vmcnt, 2 blocks/CU ----------
__global__ __launch_bounds__(512, 4) void gram_lse_kernel(const unsigned int* __restrict__ xb,
                                                          const float* __restrict__ xn,
                                                          const float* __restrict__ logvar,
                                                          float* __restrict__ se)
{
    // per buffer: A 256x64B (16 KB) at [0], B 128x64B (8 KB) at [16384]  => 72 KiB total
    __shared__ __align__(1024) unsigned char lds[3][24576];

    // decode linear block id -> (a, v): a in [0,32), v in [2a, 64)
    int rem = blockIdx.x;
    int a = 0;
    while (rem >= NTB - 2 * a) { rem -= NTB - 2 * a; ++a; }
    const int v = 2 * a + rem;

    const int tid  = threadIdx.x;           // 512
    const int lane = tid & 63;
    const int wave = tid >> 6;              // 8 waves: 4(M) x 2(N)
    const int wr = wave >> 1, wc = wave & 1;
    const int fc = lane >> 4;               // 16B chunk group 0..3

    const size_t rowA0 = (size_t)a * BMA;
    const size_t rowB0 = (size_t)v * BNB;
    const unsigned char* xb8 = (const unsigned char*)xb;

    // staging: 3 slots/thread/K-tile (2 A + 1 B), 16 B each.
    // slot element e -> row r=e>>2, chunk c=e&3; source chunk PRE-SWIZZLED
    // (c ^ (r>>1)&3); LDS dest linear (rule #21).
    unsigned int srcOff[3];
    int dstOff[3];
#pragma unroll
    for (int l = 0; l < 3; ++l) {
        const int e = (l < 2) ? (l * 512 + tid) : tid;
        const int r = e >> 2, c = e & 3;
        const int csw = c ^ ((r >> 1) & 3);
        const size_t rb = ((l < 2) ? rowA0 : rowB0) + (size_t)r;
        srcOff[l] = (unsigned int)(rb * ROW_B + (size_t)csw * 16);
        dstOff[l] = ((l < 2) ? 0 : 16384) + e * 16;
    }

    i32x4 acc[4][4];
#pragma unroll
    for (int i = 0; i < 4; ++i)
#pragma unroll
        for (int j = 0; j < 4; ++j) acc[i][j] = (i32x4){0, 0, 0, 0};

    // prologue: stage K-tiles 0 and 1 into buffers 0 and 1
#pragma unroll
    for (int l = 0; l < 3; ++l)
        __builtin_amdgcn_global_load_lds(
            (const __attribute__((address_space(1))) void*)(xb8 + srcOff[l]),
            (__attribute__((address_space(3))) void*)(&lds[0][0] + dstOff[l]), 16, 0, 0);
#pragma unroll
    for (int l = 0; l < 3; ++l)
        __builtin_amdgcn_global_load_lds(
            (const __attribute__((address_space(1))) void*)(xb8 + srcOff[l] + 64u),
            (__attribute__((address_space(3))) void*)(&lds[1][0] + dstOff[l]), 16, 0, 0);
    asm volatile("s_waitcnt vmcnt(3)" ::: "memory");   // tile 0 landed; tile 1 in flight
    asm volatile("s_barrier" ::: "memory");

    for (int t = 0; t < NKT; ++t) {
        const unsigned char* cur = &lds[t % 3][0];

        // prefetch tile t+2 into buf (t+2)%3 (its last readers finished at
        // the end of iter t-1, strictly before this point)
        if (t + 2 < NKT) {
            unsigned char* nxt = &lds[(t + 2) % 3][0];
            const unsigned int kg = (unsigned int)(t + 2) * 64u;
#pragma unroll
            for (int l = 0; l < 3; ++l)
                __builtin_amdgcn_global_load_lds(
                    (const __attribute__((address_space(1))) void*)(xb8 + srcOff[l] + kg),
                    (__attribute__((address_space(3))) void*)(nxt + dstOff[l]), 16, 0, 0);
        }

        // fragment reads (swizzled, conflict-free): one b128 = one K=64 i8 fragment
        i32x4 aF[4], bF[4];
#pragma unroll
        for (int mi = 0; mi < 4; ++mi) {
            const int r = wr * 64 + mi * 16 + (lane & 15);
            const int phys = fc ^ ((r >> 1) & 3);
            aF[mi] = *(const i32x4*)(cur + r * 64 + phys * 16);
        }
#pragma unroll
        for (int ni = 0; ni < 4; ++ni) {
            const int r = wc * 64 + ni * 16 + (lane & 15);
            const int phys = fc ^ ((r >> 1) & 3);
            bF[ni] = *(const i32x4*)(cur + 16384 + r * 64 + phys * 16);
        }

        __builtin_amdgcn_s_setprio(1);
#pragma unroll
        for (int mi = 0; mi < 4; ++mi)
#pragma unroll
            for (int ni = 0; ni < 4; ++ni)
                acc[mi][ni] = __builtin_amdgcn_mfma_i32_16x16x64_i8(
                    aF[mi], bF[ni], acc[mi][ni], 0, 0, 0);
        __builtin_amdgcn_s_setprio(0);

        // counted fence: t+1's 3 loads (older) must land; t+2's 3 may stay in flight
        if (t + 2 < NKT)
            asm volatile("s_waitcnt vmcnt(3)" ::: "memory");
        else
            asm volatile("s_waitcnt vmcnt(0)" ::: "memory");
        asm volatile("s_barrier" ::: "memory");
    }

    // ---- fused epilogue: exp terms + row/col partial sums ----
    const float lv  = logvar[0];
    const float var = __expf(lv) + 1e-10f;
    const float cc  = 0.5f / var;

    const int u = 2 * a + (wr >> 1);        // this wave's 128-row cell index
    if (u > v) return;                      // below-diagonal half of a v==2a tile

    const int colBase = (int)rowB0 + wc * 64 + (lane & 15);
    const int rowBase = (int)rowA0 + wr * 64 + (lane >> 4) * 4;

    // row sums -> se[i]  (i==j override handles diagonal cells exactly)
#pragma unroll
    for (int mi = 0; mi < 4; ++mi) {
#pragma unroll
        for (int rg = 0; rg < 4; ++rg) {
            const int i = rowBase + mi * 16 + rg;
            const float xni = xn[i];
            float rs = 0.f;
#pragma unroll
            for (int ni = 0; ni < 4; ++ni) {
                const int j = colBase + ni * 16;
                const float g = (float)acc[mi][ni][rg] * INV_S2;
                const float dist = xni + xn[j] - 2.f * g;
                rs += (i == j) ? 1.0f : __expf(-cc * fmaxf(dist, 0.f));
            }
#pragma unroll
            for (int d = 1; d < 16; d <<= 1) rs += __shfl_xor(rs, d);
            if ((lane & 15) == 0) atomicAdd(&se[i], rs);
        }
    }

    // col-mirror sums -> se[j], strictly-off-diagonal cells only (i < j always)
    if (u < v) {
#pragma unroll
        for (int ni = 0; ni < 4; ++ni) {
            const int j = colBase + ni * 16;
            const float xnj = xn[j];
            float cs = 0.f;
#pragma unroll
            for (int mi = 0; mi < 4; ++mi)
#pragma unroll
                for (int rg = 0; rg < 4; ++rg) {
                    const int i = rowBase + mi * 16 + rg;
                    const float g = (float)acc[mi][ni][rg] * INV_S2;
                    cs += __expf(-cc * fmaxf(xn[i] + xnj - 2.f * g, 0.f));
                }
#pragma unroll
            for (int d = 16; d < 64; d <<= 1) cs += __shfl_xor(cs, d);
            if ((lane >> 4) == 0) atomicAdd(&se[j], cs);
        }
    }
}

// ---------- kernel 3: KL scalar ----------
__global__ __launch_bounds__(256) void kl_kernel(const float* __restrict__ se,
                                                 float* __restrict__ out)
{
    const int tid = threadIdx.x;
    float s = 0.f;
    for (int i = tid; i < B_DIM; i += 256) s += logf(se[i]);
#pragma unroll
    for (int d = 32; d > 0; d >>= 1) s += __shfl_down(s, d);
    __shared__ float red[4];
    if ((tid & 63) == 0) red[tid >> 6] = s;
    __syncthreads();
    if (tid == 0) {
        const float dc = -(red[0] + red[1] + red[2] + red[3]) / (float)B_DIM;
        out[0] = (logf((float)B_DIM) + dc) / logf(2.f);
    }
}

// ---------- kernel 4 (fallback path only): x_t elementwise ----------
__global__ __launch_bounds__(256) void xt_kernel(const float4* __restrict__ x,
                                                 const float4* __restrict__ nz,
                                                 const float* __restrict__ logvar,
                                                 float4* __restrict__ out, int n4)
{
    const float sc = expf(0.5f * logvar[0]);
    for (int i = blockIdx.x * blockDim.x + threadIdx.x; i < n4;
         i += gridDim.x * blockDim.x) {
        float4 va = x[i], vb = nz[i];
        float4 o;
        o.x = fmaf(sc, vb.x, va.x);
        o.y = fmaf(sc, vb.y, va.y);
        o.z = fmaf(sc, vb.z, va.z);
        o.w = fmaf(sc, vb.w, va.w);
        out[i] = o;
    }
}

extern "C" void kernel_launch(void* const* d_in, const int* in_sizes, int n_in,
                              void* d_out, int out_size, void* d_ws, size_t ws_size,
                              hipStream_t stream)
{
    const float* x      = (const float*)d_in[0];
    const float* noise  = (const float*)d_in[1];
    const float* logvar = (const float*)d_in[2];
    float* out = (float*)d_out;

    const size_t NEL      = (size_t)B_DIM * K_DIM;      // 25165824
    const size_t XB_BYTES = (size_t)B_DIM * ROW_B;      // 25165824 B
    const size_t NTILES   = 1056;                       // sum_{a<32} (64-2a)

    const bool use_ws = ws_size >= XB_BYTES + 2 * (size_t)B_DIM * sizeof(float) + 256;

    if (use_ws) {
        // xb/xn/se live in d_ws; x_t written directly by fused prep
        unsigned int* xb = (unsigned int*)d_ws;
        float* xn = (float*)((char*)d_ws + XB_BYTES);
        float* se = xn + B_DIM;

        prep_kernel<<<B_DIM, 384, 0, stream>>>(x, noise, logvar, out, xb, xn, se);
        gram_lse_kernel<<<(int)NTILES, 512, 0, stream>>>(xb, xn, logvar, se);
        kl_kernel<<<1, 256, 0, stream>>>(se, out + NEL);
    } else {
        // fallback: scratch carved from d_out, x_t written last
        unsigned int* xb = (unsigned int*)d_out;
        float* xn = (float*)((char*)d_out + (32u << 20));
        float* se = xn + B_DIM;

        prep_kernel<<<B_DIM, 384, 0, stream>>>(x, noise, logvar, nullptr, xb, xn, se);
        gram_lse_kernel<<<(int)NTILES, 512, 0, stream>>>(xb, xn, logvar, se);
        kl_kernel<<<1, 256, 0, stream>>>(se, out + NEL);
        xt_kernel<<<2048, 256, 0, stream>>>((const float4*)x, (const float4*)noise,
                                            logvar, (float4*)out, (int)(NEL / 4));
    }
}